// Round 2
// baseline (26648.459 us; speedup 1.0000x reference)
//
#include <hip/hip_runtime.h>
#include <hip/hip_bf16.h>

#define N_LAYER 4
#define N_HEAD 16
#define D_MODEL 1024
#define D_HEAD 64
#define D_INNER 4096
#define TGT_LEN 512
#define MEM_LEN 512
#define KLEN (TGT_LEN + MEM_LEN)   // 1024
#define BSZ 8

typedef unsigned short ushort;

__device__ __forceinline__ float bf2f(ushort u) {
    union { unsigned int i; float f; } x; x.i = ((unsigned int)u) << 16; return x.f;
}
__device__ __forceinline__ ushort f2bf(float f) {
    unsigned int x = __float_as_uint(f);
    unsigned int r = (x + 0x7fffu + ((x >> 16) & 1u)) >> 16;
    return (ushort)r;
}
// dtype-flexible scalar load: flag!=0 -> fp32 data, flag==0 -> bf16 data
__device__ __forceinline__ float ldin(const void* p, size_t i, int fp32) {
    return fp32 ? ((const float*)p)[i] : bf2f(((const ushort*)p)[i]);
}

// ---------------------------------------------------------------------------
// Detect input float dtype by sampling emb_table. Writes 1 (fp32) or 0 (bf16).
__global__ __launch_bounds__(256) void detect_kernel(
    const ushort* __restrict__ emb_u, int* __restrict__ flag)
{
    __shared__ int cnt[256];
    int c = 0;
    for (int k = threadIdx.x; k < 4096; k += 256) {
        // element 2k if bf16-packed; low half of float k if fp32
        ushort u = emb_u[2 * k];
        int e = (u >> 7) & 0xFF;
        if (u == 0 || (e >= 96 && e <= 130)) c++;
    }
    cnt[threadIdx.x] = c; __syncthreads();
    for (int w = 128; w > 0; w >>= 1) {
        if (threadIdx.x < w) cnt[threadIdx.x] += cnt[threadIdx.x + w];
        __syncthreads();
    }
    if (threadIdx.x == 0) *flag = (cnt[0] < 2048) ? 1 : 0;
}

// ---------------------------------------------------------------------------
// core[i,b,:] = emb_table[inp[i,b]] * 32
__global__ __launch_bounds__(256) void embed_kernel(
    const int* __restrict__ inp, const void* __restrict__ emb,
    float* __restrict__ core, const int* __restrict__ flag)
{
    const int fp32 = *flag;
    const int row = blockIdx.x;
    const int t = threadIdx.x;
    const int tok = inp[row];
    float* c = core + (size_t)row * D_MODEL;
#pragma unroll
    for (int cidx = 0; cidx < 4; ++cidx) {
        int d = t + 256 * cidx;
        c[d] = ldin(emb, (size_t)tok * D_MODEL + d, fp32) * 32.0f;
    }
}

// ---------------------------------------------------------------------------
__global__ __launch_bounds__(256) void pos_kernel(float* __restrict__ pos)
{
    const int j = blockIdx.x;
    const int t = threadIdx.x;
    const float p = (float)(KLEN - 1 - j);
    const float lg = logf(10000.0f);
    float* row = pos + (size_t)j * D_MODEL;
#pragma unroll
    for (int cidx = 0; cidx < 4; ++cidx) {
        int d = t + 256 * cidx;
        int f = (d < 512) ? d : (d - 512);
        float invf = expf(-((float)(2 * f) / (float)D_MODEL) * lg);
        float a = p * invf;
        row[d] = (d < 512) ? sinf(a) : cosf(a);
    }
}

// ---------------------------------------------------------------------------
// cat = [mems_l ; core]
__global__ __launch_bounds__(256) void concat_kernel(
    const void* __restrict__ mems, size_t moff, const float* __restrict__ core,
    float* __restrict__ cat, const int* __restrict__ flag)
{
    const int fp32 = *flag;
    const int r = blockIdx.x;
    const int t = threadIdx.x;
    float* dst = cat + (size_t)r * D_MODEL;
    if (r < MEM_LEN * BSZ) {
#pragma unroll
        for (int cidx = 0; cidx < 4; ++cidx) {
            int d = t + 256 * cidx;
            dst[d] = ldin(mems, moff + (size_t)r * D_MODEL + d, fp32);
        }
    } else {
        const float* src = core + (size_t)(r - MEM_LEN * BSZ) * D_MODEL;
#pragma unroll
        for (int cidx = 0; cidx < 4; ++cidx) {
            int d = t + 256 * cidx;
            dst[d] = src[d];
        }
    }
}

// ---------------------------------------------------------------------------
// C[M,N] = A[M,K] * W[N,K]^T (+bias, +relu). A fp32, W dtype per flag, C fp32.
template<bool BIAS, bool RELU>
__global__ __launch_bounds__(256) void gemm_awt(
    const float* __restrict__ A, const void* __restrict__ W, size_t woff,
    const void* __restrict__ bias, size_t boff, float* __restrict__ C,
    int M, int N, int K, const int* __restrict__ flag)
{
    const int fp32 = *flag;
    __shared__ float As[16][65];
    __shared__ float Ws[16][65];
    const int m0 = blockIdx.y * 64;
    const int n0 = blockIdx.x * 64;
    const int t = threadIdx.x;
    const int lr = t >> 2;
    const int lc = (t & 3) << 2;
    const int tn = t & 15;
    const int tm = t >> 4;
    float acc[4][4] = {};

    for (int k0 = 0; k0 < K; k0 += 16) {
        const float4 av = *reinterpret_cast<const float4*>(
            &A[(size_t)(m0 + lr) * K + k0 + lc]);
        As[lc + 0][lr] = av.x; As[lc + 1][lr] = av.y;
        As[lc + 2][lr] = av.z; As[lc + 3][lr] = av.w;
        const size_t widx = woff + (size_t)(n0 + lr) * K + k0 + lc;
        float w0, w1, w2, w3;
        if (fp32) {
            const float4 wv = *reinterpret_cast<const float4*>((const float*)W + widx);
            w0 = wv.x; w1 = wv.y; w2 = wv.z; w3 = wv.w;
        } else {
            const ushort4 wv = *reinterpret_cast<const ushort4*>((const ushort*)W + widx);
            w0 = bf2f(wv.x); w1 = bf2f(wv.y); w2 = bf2f(wv.z); w3 = bf2f(wv.w);
        }
        Ws[lc + 0][lr] = w0; Ws[lc + 1][lr] = w1;
        Ws[lc + 2][lr] = w2; Ws[lc + 3][lr] = w3;
        __syncthreads();
#pragma unroll
        for (int kk = 0; kk < 16; ++kk) {
            float a[4], w[4];
#pragma unroll
            for (int i = 0; i < 4; ++i) a[i] = As[kk][tm * 4 + i];
#pragma unroll
            for (int j = 0; j < 4; ++j) w[j] = Ws[kk][tn * 4 + j];
#pragma unroll
            for (int i = 0; i < 4; ++i)
#pragma unroll
                for (int j = 0; j < 4; ++j)
                    acc[i][j] += a[i] * w[j];
        }
        __syncthreads();
    }

#pragma unroll
    for (int i = 0; i < 4; ++i) {
        const int m = m0 + tm * 4 + i;
#pragma unroll
        for (int j = 0; j < 4; ++j) {
            const int n = n0 + tn * 4 + j;
            float v = acc[i][j];
            if (BIAS) v += ldin(bias, boff + n, fp32);
            if (RELU) v = fmaxf(v, 0.0f);
            C[(size_t)m * N + n] = v;
        }
    }
}

// ---------------------------------------------------------------------------
// Fused relative attention, one block per (i, b, n).
__global__ __launch_bounds__(256) void attn_kernel(
    const float* __restrict__ q, const float* __restrict__ k,
    const float* __restrict__ v, const float* __restrict__ rk,
    const void* __restrict__ rwb, const void* __restrict__ rrb,
    float* __restrict__ vec, const int* __restrict__ flag)
{
    const int fp32 = *flag;
    const int i = blockIdx.x;
    const int b = blockIdx.y;
    const int n = blockIdx.z;
    const int t = threadIdx.x;

    __shared__ float qw[64], qr[64];
    __shared__ float probs[KLEN];
    __shared__ float sm[256];
    __shared__ float red2[4][64];

    if (t < 64) {
        float qv = q[((size_t)(i * BSZ + b)) * D_MODEL + n * 64 + t];
        qw[t] = qv + ldin(rwb, n * 64 + t, fp32);
        qr[t] = qv + ldin(rrb, n * 64 + t, fp32);
    }
    __syncthreads();

    const int jmax = i + MEM_LEN;
    float s[4];
    float mymax = -1e30f;
#pragma unroll
    for (int c = 0; c < 4; ++c) {
        const int j = t + 256 * c;
        float sc = -1e30f;
        if (j <= jmax) {
            const int jj = j + TGT_LEN - 1 - i;
            const float* kp = &k[((size_t)j * BSZ + b) * D_MODEL + n * 64];
            const float* rp = &rk[(size_t)jj * D_MODEL + n * 64];
            float ac = 0.f, bd = 0.f;
#pragma unroll
            for (int d = 0; d < 64; ++d) {
                ac += qw[d] * kp[d];
                bd += qr[d] * rp[d];
            }
            sc = (ac + bd) * 0.125f;
        }
        s[c] = sc;
        mymax = fmaxf(mymax, sc);
    }

    sm[t] = mymax; __syncthreads();
    for (int w = 128; w > 0; w >>= 1) {
        if (t < w) sm[t] = fmaxf(sm[t], sm[t + w]);
        __syncthreads();
    }
    const float bmax = sm[0];
    __syncthreads();

    float mysum = 0.f;
#pragma unroll
    for (int c = 0; c < 4; ++c) {
        const int j = t + 256 * c;
        float e = (s[c] > -1e29f) ? expf(s[c] - bmax) : 0.f;
        probs[j] = e;
        mysum += e;
    }
    sm[t] = mysum; __syncthreads();
    for (int w = 128; w > 0; w >>= 1) {
        if (t < w) sm[t] += sm[t + w];
        __syncthreads();
    }
    const float inv = 1.0f / sm[0];
    __syncthreads();

    const int d = t & 63;
    const int ch = t >> 6;
    const int jend = min(ch * 256 + 256, jmax + 1);
    float partial = 0.f;
    for (int j = ch * 256; j < jend; ++j) {
        partial += probs[j] * v[((size_t)j * BSZ + b) * D_MODEL + n * 64 + d];
    }
    red2[ch][d] = partial;
    __syncthreads();
    if (t < 64) {
        float o = (red2[0][t] + red2[1][t] + red2[2][t] + red2[3][t]) * inv;
        vec[((size_t)(i * BSZ + b)) * D_MODEL + n * 64 + t] = o;
    }
}

// ---------------------------------------------------------------------------
// core = LayerNorm(core + resid) * g + b  (in place), one block per row
__global__ __launch_bounds__(256) void add_ln_kernel(
    float* __restrict__ core, const float* __restrict__ resid,
    const void* __restrict__ g, size_t goff,
    const void* __restrict__ bta, size_t boff, const int* __restrict__ flag)
{
    const int fp32 = *flag;
    const int row = blockIdx.x;
    const int t = threadIdx.x;
    __shared__ float sm[256];
    float x[4];
    float sum = 0.f;
    float* c = core + (size_t)row * D_MODEL;
    const float* r = resid + (size_t)row * D_MODEL;
#pragma unroll
    for (int ci = 0; ci < 4; ++ci) {
        int d = t + 256 * ci;
        x[ci] = c[d] + r[d];
        sum += x[ci];
    }
    sm[t] = sum; __syncthreads();
    for (int w = 128; w > 0; w >>= 1) {
        if (t < w) sm[t] += sm[t + w];
        __syncthreads();
    }
    const float mean = sm[0] * (1.0f / D_MODEL);
    __syncthreads();
    float vs = 0.f;
#pragma unroll
    for (int ci = 0; ci < 4; ++ci) {
        float dlt = x[ci] - mean;
        vs += dlt * dlt;
    }
    sm[t] = vs; __syncthreads();
    for (int w = 128; w > 0; w >>= 1) {
        if (t < w) sm[t] += sm[t + w];
        __syncthreads();
    }
    const float rstd = rsqrtf(sm[0] * (1.0f / D_MODEL) + 1e-5f);
    __syncthreads();
#pragma unroll
    for (int ci = 0; ci < 4; ++ci) {
        int d = t + 256 * ci;
        c[d] = (x[ci] - mean) * rstd * ldin(g, goff + d, fp32) + ldin(bta, boff + d, fp32);
    }
}

// ---------------------------------------------------------------------------
__global__ __launch_bounds__(256) void cast_out_kernel(
    const float* __restrict__ core, void* __restrict__ out,
    const int* __restrict__ flag)
{
    const int fp32 = *flag;
    const int idx = blockIdx.x * 256 + threadIdx.x;
    if (fp32) ((float*)out)[idx] = core[idx];
    else      ((ushort*)out)[idx] = f2bf(core[idx]);
}

// ---------------------------------------------------------------------------
extern "C" void kernel_launch(void* const* d_in, const int* in_sizes, int n_in,
                              void* d_out, int out_size, void* d_ws, size_t ws_size,
                              hipStream_t stream)
{
    const int*  inp      = (const int*)d_in[0];
    const void* mems     = d_in[1];
    const void* emb      = d_in[2];
    const void* r_w_bias = d_in[3];
    const void* r_r_bias = d_in[4];
    const void* qkv_w    = d_in[5];
    const void* r_w      = d_in[6];
    const void* o_w      = d_in[7];
    const void* ln1_g    = d_in[8];
    const void* ln1_b    = d_in[9];
    const void* ff_w1    = d_in[10];
    const void* ff_b1    = d_in[11];
    const void* ff_w2    = d_in[12];
    const void* ff_b2    = d_in[13];
    const void* ln2_g    = d_in[14];
    const void* ln2_b    = d_in[15];

    int* flag = (int*)d_ws;
    float* ws = (float*)d_ws + 256;          // keep 16B alignment, skip flag area
    size_t off = 0;
    float* core = ws + off; off += (size_t)TGT_LEN * BSZ * D_MODEL;
    float* X    = ws + off; off += (size_t)TGT_LEN * BSZ * D_INNER;
    float* qb   = ws + off; off += (size_t)TGT_LEN * BSZ * D_MODEL;
    float* kb   = ws + off; off += (size_t)KLEN * BSZ * D_MODEL;
    float* vb   = ws + off; off += (size_t)KLEN * BSZ * D_MODEL;
    float* rkb  = ws + off; off += (size_t)KLEN * D_MODEL;
    float* posb = ws + off; off += (size_t)KLEN * D_MODEL;
    float* vecb = ws + off; off += (size_t)TGT_LEN * BSZ * D_MODEL;

    float* cat      = X;
    float* attn_out = X;
    float* h1       = X;
    float* ffb      = vecb;

    detect_kernel<<<1, 256, 0, stream>>>((const ushort*)emb, flag);
    embed_kernel<<<TGT_LEN * BSZ, 256, 0, stream>>>(inp, emb, core, flag);
    pos_kernel<<<KLEN, 256, 0, stream>>>(posb);

    for (int l = 0; l < N_LAYER; ++l) {
        const size_t qkv_off = (size_t)l * 3 * D_MODEL * D_MODEL;
        const size_t rw_off  = (size_t)l * D_MODEL * D_MODEL;
        const size_t ow_off  = (size_t)l * D_MODEL * D_MODEL;
        const size_t w1_off  = (size_t)l * D_INNER * D_MODEL;
        const size_t b1_off  = (size_t)l * D_INNER;
        const size_t w2_off  = (size_t)l * D_MODEL * D_INNER;
        const size_t b2_off  = (size_t)l * D_MODEL;
        const size_t mems_off = (size_t)l * MEM_LEN * BSZ * D_MODEL;
        const size_t ln_off  = (size_t)l * D_MODEL;

        concat_kernel<<<KLEN * BSZ, 256, 0, stream>>>(mems, mems_off, core, cat, flag);

        gemm_awt<false, false><<<dim3(D_MODEL / 64, (TGT_LEN * BSZ) / 64), 256, 0, stream>>>(
            cat + (size_t)MEM_LEN * BSZ * D_MODEL, qkv_w, qkv_off, nullptr, 0, qb,
            TGT_LEN * BSZ, D_MODEL, D_MODEL, flag);
        gemm_awt<false, false><<<dim3(D_MODEL / 64, (KLEN * BSZ) / 64), 256, 0, stream>>>(
            cat, qkv_w, qkv_off + (size_t)D_MODEL * D_MODEL, nullptr, 0, kb,
            KLEN * BSZ, D_MODEL, D_MODEL, flag);
        gemm_awt<false, false><<<dim3(D_MODEL / 64, (KLEN * BSZ) / 64), 256, 0, stream>>>(
            cat, qkv_w, qkv_off + (size_t)2 * D_MODEL * D_MODEL, nullptr, 0, vb,
            KLEN * BSZ, D_MODEL, D_MODEL, flag);
        gemm_awt<false, false><<<dim3(D_MODEL / 64, KLEN / 64), 256, 0, stream>>>(
            posb, r_w, rw_off, nullptr, 0, rkb, KLEN, D_MODEL, D_MODEL, flag);

        attn_kernel<<<dim3(TGT_LEN, BSZ, N_HEAD), 256, 0, stream>>>(
            qb, kb, vb, rkb, r_w_bias, r_r_bias, vecb, flag);

        gemm_awt<false, false><<<dim3(D_MODEL / 64, (TGT_LEN * BSZ) / 64), 256, 0, stream>>>(
            vecb, o_w, ow_off, nullptr, 0, attn_out, TGT_LEN * BSZ, D_MODEL, D_MODEL, flag);

        add_ln_kernel<<<TGT_LEN * BSZ, 256, 0, stream>>>(core, attn_out,
            ln1_g, ln_off, ln1_b, ln_off, flag);

        gemm_awt<true, true><<<dim3(D_INNER / 64, (TGT_LEN * BSZ) / 64), 256, 0, stream>>>(
            core, ff_w1, w1_off, ff_b1, b1_off, h1, TGT_LEN * BSZ, D_INNER, D_MODEL, flag);
        gemm_awt<true, false><<<dim3(D_MODEL / 64, (TGT_LEN * BSZ) / 64), 256, 0, stream>>>(
            h1, ff_w2, w2_off, ff_b2, b2_off, ffb, TGT_LEN * BSZ, D_MODEL, D_INNER, flag);

        add_ln_kernel<<<TGT_LEN * BSZ, 256, 0, stream>>>(core, ffb,
            ln2_g, ln_off, ln2_b, ln_off, flag);
    }

    cast_out_kernel<<<(TGT_LEN * BSZ * D_MODEL) / 256, 256, 0, stream>>>(
        core, d_out, flag);
}